// Round 1
// baseline (38725.104 us; speedup 1.0000x reference)
//
#include <hip/hip_runtime.h>
#include <math.h>

// GRUDetector: B=1024, T=512, F=64, H=128, gates (r,z,n), + MLP head (H->32->1).
// Strategy: batch rows independent -> 256 blocks x NB=4 rows, persistent loop over T.
// Weights register-resident: thread g (0..383) owns gate row g:
//   W_ih[g][0:64] + W_hh[g][0:128] = 192 fp32 VGPRs, fully unrolled (static idx).
// h and x_t live in LDS; GEMV reads are wave-uniform (broadcast, conflict-free).

#define Bsz  1024
#define Tlen 512
#define Fdim 64
#define Hdim 128
#define Gdim 384   // 3*H
#define NB   4

__global__ __launch_bounds__(384, 2)
void gru_persist(const float* __restrict__ x,
                 const float* __restrict__ W_ih, const float* __restrict__ W_hh,
                 const float* __restrict__ b_ih, const float* __restrict__ b_hh,
                 const float* __restrict__ W1, const float* __restrict__ b1,
                 const float* __restrict__ W2, const float* __restrict__ b2,
                 float* __restrict__ out)
{
    __shared__ float h_lds[NB][Hdim];      // 2 KB
    __shared__ float x_lds[NB][Fdim];      // 1 KB
    __shared__ float xg_lds[NB][Gdim];     // 6 KB
    __shared__ float hg_lds[NB][Gdim];     // 6 KB
    __shared__ float hid_lds[NB][32];

    const int tid = threadIdx.x;
    const int g   = tid;                   // gate row 0..383
    const int b0  = blockIdx.x * NB;

    // ---- load this thread's weight rows into registers (one-time, vectorized)
    float wih[Fdim];
    float whh[Hdim];
    {
        const float4* p = reinterpret_cast<const float4*>(W_ih + (size_t)g * Fdim);
        #pragma unroll
        for (int j = 0; j < Fdim/4; ++j) {
            float4 v = p[j];
            wih[4*j+0] = v.x; wih[4*j+1] = v.y; wih[4*j+2] = v.z; wih[4*j+3] = v.w;
        }
        const float4* q = reinterpret_cast<const float4*>(W_hh + (size_t)g * Hdim);
        #pragma unroll
        for (int k = 0; k < Hdim/4; ++k) {
            float4 v = q[k];
            whh[4*k+0] = v.x; whh[4*k+1] = v.y; whh[4*k+2] = v.z; whh[4*k+3] = v.w;
        }
    }
    const float bi = b_ih[g];
    const float bh = b_hh[g];

    // ---- init h = 0 and stage x(t=0)
    for (int i = tid; i < NB*Hdim; i += Gdim) h_lds[i >> 7][i & 127] = 0.f;
    if (tid < NB*Fdim) {
        int b = tid >> 6, j = tid & 63;
        x_lds[b][j] = x[((size_t)(b0 + b) * Tlen) * Fdim + j];
    }
    __syncthreads();

    for (int t = 0; t < Tlen; ++t) {
        // ---- GEMV phase: thread g computes xg[b][g], hg[b][g] for all NB rows
        #pragma unroll 1
        for (int b = 0; b < NB; ++b) {
            float xacc = bi, hacc = bh;
            #pragma unroll
            for (int j = 0; j < Fdim; ++j) xacc += wih[j] * x_lds[b][j];
            #pragma unroll
            for (int k = 0; k < Hdim; ++k) hacc += whh[k] * h_lds[b][k];
            xg_lds[b][g] = xacc;
            hg_lds[b][g] = hacc;
        }
        __syncthreads();

        // ---- gate/update phase (512 slots over 384 threads) + stage next x
        for (int i = tid; i < NB*Hdim; i += Gdim) {
            int b = i >> 7, k = i & 127;
            float xr = xg_lds[b][k],          hr = hg_lds[b][k];
            float xz = xg_lds[b][Hdim + k],   hz = hg_lds[b][Hdim + k];
            float xn = xg_lds[b][2*Hdim + k], hn = hg_lds[b][2*Hdim + k];
            float r = 1.f / (1.f + expf(-(xr + hr)));
            float z = 1.f / (1.f + expf(-(xz + hz)));
            float n = tanhf(xn + r * hn);
            h_lds[b][k] = (1.f - z) * n + z * h_lds[b][k];
        }
        if (t + 1 < Tlen && tid < NB*Fdim) {
            int b = tid >> 6, j = tid & 63;
            x_lds[b][j] = x[((size_t)(b0 + b) * Tlen + (t+1)) * Fdim + j];
        }
        __syncthreads();
    }

    // ---- epilogue MLP: hidden = relu(h @ W1.T + b1); out = hidden @ W2.T + b2
    if (tid < NB*32) {
        int b = tid >> 5, u = tid & 31;
        float a = b1[u];
        #pragma unroll
        for (int k = 0; k < Hdim; ++k) a += W1[u*Hdim + k] * h_lds[b][k];
        hid_lds[b][u] = fmaxf(a, 0.f);
    }
    __syncthreads();
    if (tid < NB) {
        float a = b2[0];
        #pragma unroll
        for (int u = 0; u < 32; ++u) a += W2[u] * hid_lds[tid][u];
        out[b0 + tid] = a;
    }
}

extern "C" void kernel_launch(void* const* d_in, const int* in_sizes, int n_in,
                              void* d_out, int out_size, void* d_ws, size_t ws_size,
                              hipStream_t stream)
{
    const float* x    = (const float*)d_in[0];
    const float* W_ih = (const float*)d_in[1];
    const float* W_hh = (const float*)d_in[2];
    const float* b_ih = (const float*)d_in[3];
    const float* b_hh = (const float*)d_in[4];
    const float* W1   = (const float*)d_in[5];
    const float* b1   = (const float*)d_in[6];
    const float* W2   = (const float*)d_in[7];
    const float* b2   = (const float*)d_in[8];
    float* out = (float*)d_out;

    dim3 grid(Bsz / NB), block(Gdim);
    hipLaunchKernelGGL(gru_persist, grid, block, 0, stream,
                       x, W_ih, W_hh, b_ih, b_hh, W1, b1, W2, b2, out);
}

// Round 2
// 33734.766 us; speedup vs baseline: 1.1479x; 1.1479x over previous
//
#include <hip/hip_runtime.h>
#include <math.h>

// GRUDetector: B=1024, T=512, F=64, H=128, gates (r,z,n), + MLP head (H->32->1).
// R2: fix register spill from R1 (128-VGPR cap spilled 192-float weight array ->
// 66 GB scratch traffic). Now 2 threads per gate row: thread (g, half) holds
// W_ih[g][half*32 +: 32] + W_hh[g][half*64 +: 64] = 96 fp32 VGPRs, static idx.
// Block = 768 thr = 12 waves = 3/SIMD (even), launch_bounds(768,3) -> VGPR<=168.
// 256 blocks = exactly 1 per CU. h/x in LDS (2-addr wave broadcast = free).

#define Bsz  1024
#define Tlen 512
#define Fdim 64
#define Hdim 128
#define Gdim 384   // 3*H
#define NB   4
#define NTHR 768

__device__ __forceinline__ float fast_sigmoid(float v) {
    return __builtin_amdgcn_rcpf(1.f + __expf(-v));
}
__device__ __forceinline__ float fast_tanh(float v) {
    // 1 - 2/(e^{2v}+1): saturates correctly at +-inf (no inf/inf NaN)
    return 1.f - 2.f * __builtin_amdgcn_rcpf(__expf(2.f * v) + 1.f);
}

__global__ __launch_bounds__(NTHR, 3)
void gru_persist(const float* __restrict__ x,
                 const float* __restrict__ W_ih, const float* __restrict__ W_hh,
                 const float* __restrict__ b_ih, const float* __restrict__ b_hh,
                 const float* __restrict__ W1, const float* __restrict__ b1,
                 const float* __restrict__ W2, const float* __restrict__ b2,
                 float* __restrict__ out)
{
    __shared__ float h_lds[NB][Hdim];      // 2 KB
    __shared__ float x_lds[NB][Fdim];      // 1 KB
    __shared__ float xg_lds[NB][Gdim];     // 6 KB
    __shared__ float hg_lds[NB][Gdim];     // 6 KB
    __shared__ float hid_lds[NB][32];

    const int tid  = threadIdx.x;
    const int g    = tid >> 1;             // gate row 0..383
    const int half = tid & 1;              // which half of the dot product
    const int b0   = blockIdx.x * NB;

    // ---- one-time: this thread's half weight rows into registers (96 fp32)
    float wih[Fdim / 2];                   // 32
    float whh[Hdim / 2];                   // 64
    {
        const float4* p = reinterpret_cast<const float4*>(
            W_ih + (size_t)g * Fdim + half * (Fdim / 2));
        #pragma unroll
        for (int j = 0; j < Fdim / 8; ++j) {
            float4 v = p[j];
            wih[4*j+0] = v.x; wih[4*j+1] = v.y; wih[4*j+2] = v.z; wih[4*j+3] = v.w;
        }
        const float4* q = reinterpret_cast<const float4*>(
            W_hh + (size_t)g * Hdim + half * (Hdim / 2));
        #pragma unroll
        for (int k = 0; k < Hdim / 8; ++k) {
            float4 v = q[k];
            whh[4*k+0] = v.x; whh[4*k+1] = v.y; whh[4*k+2] = v.z; whh[4*k+3] = v.w;
        }
    }
    const float bi = half ? 0.f : b_ih[g];  // bias contributed by half 0 only
    const float bh = half ? 0.f : b_hh[g];

    // ---- init h = 0 and stage x(t=0)
    for (int i = tid; i < NB * Hdim; i += NTHR) h_lds[i >> 7][i & 127] = 0.f;
    if (tid < NB * Fdim) {
        int b = tid >> 6, j = tid & 63;
        x_lds[b][j] = x[((size_t)(b0 + b) * Tlen) * Fdim + j];
    }
    __syncthreads();

    for (int t = 0; t < Tlen; ++t) {
        // ---- prefetch x(t+1) into registers (waves 8..11), issued before GEMV
        float xpref = 0.f;
        if (tid >= 512 && t + 1 < Tlen) {
            int i = tid - 512, b = i >> 6, j = i & 63;
            xpref = x[((size_t)(b0 + b) * Tlen + (t + 1)) * Fdim + j];
        }

        // ---- GEMV phase: thread (g,half) computes half-dots for NB rows
        float xacc[NB], hacc[NB];
        #pragma unroll
        for (int b = 0; b < NB; ++b) { xacc[b] = bi; hacc[b] = bh; }

        #pragma unroll
        for (int kc = 0; kc < Hdim / 2; kc += 4) {
            #pragma unroll
            for (int b = 0; b < NB; ++b) {           // 4 independent FMA chains
                float4 hv = *reinterpret_cast<const float4*>(
                    &h_lds[b][half * (Hdim / 2) + kc]);
                hacc[b] += whh[kc+0] * hv.x + whh[kc+1] * hv.y
                         + whh[kc+2] * hv.z + whh[kc+3] * hv.w;
            }
        }
        #pragma unroll
        for (int jc = 0; jc < Fdim / 2; jc += 4) {
            #pragma unroll
            for (int b = 0; b < NB; ++b) {
                float4 xv = *reinterpret_cast<const float4*>(
                    &x_lds[b][half * (Fdim / 2) + jc]);
                xacc[b] += wih[jc+0] * xv.x + wih[jc+1] * xv.y
                         + wih[jc+2] * xv.z + wih[jc+3] * xv.w;
            }
        }
        // combine halves (lanes 2g <-> 2g+1) and write gate pre-activations
        #pragma unroll
        for (int b = 0; b < NB; ++b) {
            float xs = xacc[b] + __shfl_xor(xacc[b], 1, 64);
            float hs = hacc[b] + __shfl_xor(hacc[b], 1, 64);
            if (half == 0) xg_lds[b][g] = xs;
            else           hg_lds[b][g] = hs;
        }
        __syncthreads();

        // ---- gate/update phase (waves 0..7) ; x write-back (waves 8..11)
        if (tid < NB * Hdim) {
            int b = tid >> 7, k = tid & 127;
            float xr = xg_lds[b][k],            hr = hg_lds[b][k];
            float xz = xg_lds[b][Hdim + k],     hz = hg_lds[b][Hdim + k];
            float xn = xg_lds[b][2*Hdim + k],   hn = hg_lds[b][2*Hdim + k];
            float r = fast_sigmoid(xr + hr);
            float z = fast_sigmoid(xz + hz);
            float n = fast_tanh(xn + r * hn);
            h_lds[b][k] = (1.f - z) * n + z * h_lds[b][k];
        } else if (t + 1 < Tlen) {
            int i = tid - 512, b = i >> 6, j = i & 63;
            x_lds[b][j] = xpref;
        }
        __syncthreads();
    }

    // ---- epilogue MLP: hidden = relu(h @ W1.T + b1); out = hidden @ W2.T + b2
    if (tid < NB * 32) {
        int b = tid >> 5, u = tid & 31;
        float a = b1[u];
        #pragma unroll
        for (int k = 0; k < Hdim; ++k) a += W1[u * Hdim + k] * h_lds[b][k];
        hid_lds[b][u] = fmaxf(a, 0.f);
    }
    __syncthreads();
    if (tid < NB) {
        float a = b2[0];
        #pragma unroll
        for (int u = 0; u < 32; ++u) a += W2[u] * hid_lds[tid][u];
        out[b0 + tid] = a;
    }
}

extern "C" void kernel_launch(void* const* d_in, const int* in_sizes, int n_in,
                              void* d_out, int out_size, void* d_ws, size_t ws_size,
                              hipStream_t stream)
{
    const float* x    = (const float*)d_in[0];
    const float* W_ih = (const float*)d_in[1];
    const float* W_hh = (const float*)d_in[2];
    const float* b_ih = (const float*)d_in[3];
    const float* b_hh = (const float*)d_in[4];
    const float* W1   = (const float*)d_in[5];
    const float* b1   = (const float*)d_in[6];
    const float* W2   = (const float*)d_in[7];
    const float* b2   = (const float*)d_in[8];
    float* out = (float*)d_out;

    dim3 grid(Bsz / NB), block(NTHR);
    hipLaunchKernelGGL(gru_persist, grid, block, 0, stream,
                       x, W_ih, W_hh, b_ih, b_hh, W1, b1, W2, b2, out);
}